// Round 18
// baseline (65.936 us; speedup 1.0000x reference)
//
#include <hip/hip_runtime.h>
#include <hip/hip_bf16.h>

#define LEN   2048
#define KNB   32
#define HID   128
#define FS    440            // fp8 bytes/feature-row; 110 dw % 32 = 14 -> uniform banks
#define FBSZ  (32 * FS)      // 14080 B per feature buffer
#define NST   19             // natoms bf16 stride: 38B -> ~2-way max (free, m136)

typedef unsigned long long ull;
typedef unsigned int uint32;
typedef float f32x4  __attribute__((ext_vector_type(4)));
typedef float f32x16 __attribute__((ext_vector_type(16)));

// LDS-only barrier: output stores (vmcnt) stay in flight across rows.
__device__ __forceinline__ void bar_lgkm() {
    asm volatile("s_waitcnt lgkmcnt(0)" ::: "memory");
    __builtin_amdgcn_s_barrier();
    asm volatile("" ::: "memory");
}

// ---------------------------------------------------------------------------
// Kernel 1: blocks 0..1023 — top-K=32 for 4 rows/block. One shared X pass:
// packed {CA.xyz, penalty} staged to LDS (bit-identical values -> selection
// exact), then 4 histogram-select rounds reading LDS. Cuts aggregate X
// re-reads 268->33.5 MB (topk was L2-read-bound). Blocks 1024+ — W->fp8.
// ---------------------------------------------------------------------------
__global__ __launch_bounds__(256) void topk_kernel(
    const float* __restrict__ X, const float* __restrict__ mask,
    const float* __restrict__ W_edge, int* __restrict__ Wf8,
    float* __restrict__ eidx_out) {
    const int bid = blockIdx.x;
    const int tid = threadIdx.x;

    if (bid >= 1024) {    // W-convert tail blocks
        const int t = (bid - 1024) * 256 + tid;
        if (t < 13312) {
            const float4 w = ((const float4*)W_edge)[t];
            int r = __builtin_amdgcn_cvt_pk_fp8_f32(w.x, w.y, 0, false);
            r = __builtin_amdgcn_cvt_pk_fp8_f32(w.z, w.w, r, true);
            Wf8[t] = r;
        }
        return;
    }

    const int row0 = bid * 4;
    const int b = row0 >> 11;                 // 2048 % 4 == 0: no batch straddle
    const int i0 = row0 & (LEN - 1);

    __shared__ __align__(16) float4 caL[LEN]; // 32768 B: {CA.x, CA.y, CA.z, pen}
    __shared__ int hist[512];                 //  2048 B
    __shared__ ull cand[LEN];                 // 16384 B
    __shared__ int candcnt;
    __shared__ int selB;
    // total ~51.2 KB -> 3 blocks/CU

    const float* Xb = X + (size_t)b * LEN * 12;
    const float* mb = mask + (size_t)b * LEN;

    // --- stage packed CA + penalty (one X pass for all 4 rows)
#pragma unroll
    for (int q = 0; q < 8; ++q) {
        const int j = q * 256 + tid;
        const float4 ld0 = *(const float4*)(Xb + j * 12);      // N.x N.y N.z CA.x
        const float4 ld1 = *(const float4*)(Xb + j * 12 + 4);  // CA.y CA.z C.x C.y
        caL[j] = make_float4(ld0.w, ld1.x, ld1.y,
                             __fmul_rn(__fsub_rn(1.0f, mb[j]), 1000000.0f));
    }
    __syncthreads();

    for (int r = 0; r < 4; ++r) {
        const float4 ci = caL[i0 + r];

        uint32 d2b[8];
#pragma unroll
        for (int q = 0; q < 8; ++q) {
            const float4 cj = caL[q * 256 + tid];
            float dx = __fsub_rn(ci.x, cj.x);
            float dy = __fsub_rn(ci.y, cj.y);
            float dz = __fsub_rn(ci.z, cj.z);
            float d2 = __fadd_rn(__fadd_rn(__fmul_rn(dx, dx), __fmul_rn(dy, dy)),
                                 __fmul_rn(dz, dz));
            d2 = __fadd_rn(d2, cj.w);
            d2b[q] = __float_as_uint(d2);
        }

        hist[tid] = 0; hist[tid + 256] = 0;
        if (tid == 0) candcnt = 0;
        __syncthreads();
#pragma unroll
        for (int q = 0; q < 8; ++q) atomicAdd(&hist[d2b[q] >> 22], 1);
        __syncthreads();

        if (tid < 64) {
            int loc[8];
            int s = 0;
#pragma unroll
            for (int t = 0; t < 8; ++t) { loc[t] = hist[tid * 8 + t]; s += loc[t]; }
            int incl = s;
#pragma unroll
            for (int off = 1; off < 64; off <<= 1) {
                int o = __shfl_up(incl, off, 64);
                if (tid >= off) incl += o;
            }
            const int excl = incl - s;
            if (excl < KNB && incl >= KNB) {
                int c = excl;
#pragma unroll
                for (int t = 0; t < 8; ++t) {
                    int c2 = c + loc[t];
                    if (c < KNB && c2 >= KNB) selB = tid * 8 + t;
                    c = c2;
                }
            }
        }
        __syncthreads();
        const uint32 B = (uint32)selB;

#pragma unroll
        for (int q = 0; q < 8; ++q) {
            if ((d2b[q] >> 22) <= B) {
                int p = atomicAdd(&candcnt, 1);
                cand[p] = (((ull)d2b[q]) << 32) | (uint32)(q * 256 + tid);
            }
        }
        __syncthreads();
        const int M = candcnt;

        for (int c = tid; c < M; c += 256) {
            const ull k = cand[c];
            int rk = 0;
            for (int m = 0; m < M; ++m) rk += (cand[m] < k);
            if (rk < KNB)
                eidx_out[(size_t)(row0 + r) * KNB + rk] =
                    (float)(uint32)(k & 0xFFFFFFFFull);
        }
        __syncthreads();   // hist/cand reused next round
    }
}

// ---------------------------------------------------------------------------
// Kernel 2: 256 thr (4 waves), 4 rows/block, 1024 blocks -> 4 blocks/CU.
// Per row, ONE barrier: [LN(prev acc) | GEMM(cur, setprio-boosted) |
// features(next) | partials ping-pong] bar. W reg-resident fp8 (52 VGPR);
// atoms bf16 @ stride 19 (conflict-free).
// ---------------------------------------------------------------------------
__device__ __forceinline__ void load_res_atoms_bf(const float* __restrict__ p, __bf16* dst) {
    const float Nx = p[0], Ny = p[1], Nz = p[2];
    const float Ax = p[3], Ay = p[4], Az = p[5];
    const float Cx = p[6], Cy = p[7], Cz = p[8];
    const float Ox = p[9], Oy = p[10], Oz = p[11];
    const float bx = Ax - Nx, by = Ay - Ny, bz = Az - Nz;
    const float cx = Cx - Ax, cy = Cy - Ay, cz = Cz - Az;
    const float axv = by * cz - bz * cy;
    const float ayv = bz * cx - bx * cz;
    const float azv = bx * cy - by * cx;
    dst[0] = (__bf16)Nx;  dst[1] = (__bf16)Ny;  dst[2] = (__bf16)Nz;
    dst[3] = (__bf16)Ax;  dst[4] = (__bf16)Ay;  dst[5] = (__bf16)Az;
    dst[6] = (__bf16)Cx;  dst[7] = (__bf16)Cy;  dst[8] = (__bf16)Cz;
    dst[9] = (__bf16)Ox;  dst[10] = (__bf16)Oy; dst[11] = (__bf16)Oz;
    dst[12] = (__bf16)(-0.58273431f * axv + 0.56802827f * bx + -0.54067466f * cx + Ax);
    dst[13] = (__bf16)(-0.58273431f * ayv + 0.56802827f * by + -0.54067466f * cy + Ay);
    dst[14] = (__bf16)(-0.58273431f * azv + 0.56802827f * bz + -0.54067466f * cz + Az);
}

__device__ __forceinline__ int pk4(float a, float b, float c, float d) {
    int r = __builtin_amdgcn_cvt_pk_fp8_f32(a, b, 0, false);
    return __builtin_amdgcn_cvt_pk_fp8_f32(c, d, r, true);
}

// chain constants exp(-1.1377778 * (2j+1)), j = 0..3
#define E1  3.2053337e-1f
#define E3  3.2931300e-2f
#define E5  3.3834001e-3f
#define E7  3.4760500e-4f

__device__ __forceinline__ void compute_features(
    int tid, int Ri, int Ci,
    const __bf16* __restrict__ wposL,
    const int* jR, const int* jC,
    const __bf16 (*natoms)[NST], const __bf16* iatoms,
    unsigned char* featF8) {
#pragma unroll
    for (int it = 0; it < 2; ++it) {           // pos-enc: 512 tasks
        const int task = tid + it * 256;
        const int e = task >> 4, p = task & 15;
        const int drel = jR[e] - Ri;
        const int same = (jC[e] == Ci);
        int dc = drel + 32;
        dc = dc < 0 ? 0 : (dc > 64 ? 64 : dc);
        const int df = same ? dc : 65;
        const float v = (float)wposL[p * 66 + df];
        const int pb = __builtin_amdgcn_cvt_pk_fp8_f32(v, 0.0f, 0, false);
        featF8[e * FS + p] = (unsigned char)(pb & 0xFF);
    }
    for (int task = tid; task < 800; task += 256) {   // rbf: 800 tasks
        const int mn = task >> 5, e = task & 31;
        const int m = mn / 5, n = mn - m * 5;
        const float ax = (float)iatoms[m * 3 + 0];
        const float ay = (float)iatoms[m * 3 + 1];
        const float az = (float)iatoms[m * 3 + 2];
        const float dx = ax - (float)natoms[e][n * 3 + 0];
        const float dy = ay - (float)natoms[e][n * 3 + 1];
        const float dz = az - (float)natoms[e][n * 3 + 2];
        const float D = sqrtf(dx * dx + dy * dy + dz * dz + 1e-6f);
        const float Dc = fminf(D, 40.0f);
        const float v4 = Dc - 7.3333333f;
        const float A4  = __expf(-0.64f * v4 * v4);
        const float C4  = __expf(1.7066667f * v4);
        const float Ci4 = 1.0f / C4;
        ull lo, hi2;
        {
            const float f3 = A4 * Ci4 * E1;
            const float f2 = f3 * Ci4 * E3;
            const float f1 = f2 * Ci4 * E5;
            const float f0 = f1 * Ci4 * E7;
            const float f5 = A4 * C4 * E1;
            const float f6 = f5 * C4 * E3;
            const float f7 = f6 * C4 * E5;
            lo = (uint32)pk4(f0, f1, f2, f3)
               | ((ull)(uint32)pk4(A4, f5, f6, f7) << 32);
        }
        const float v12 = Dc - 18.0f;
        const float A12  = __expf(-0.64f * v12 * v12);
        const float C12  = C4 * 1.24140e-8f;
        const float Ci12 = Ci4 * 8.05543e7f;
        {
            const float f11 = A12 * Ci12 * E1;
            const float f10 = f11 * Ci12 * E3;
            const float f9  = f10 * Ci12 * E5;
            const float f8  = f9  * Ci12 * E7;
            const float f13 = A12 * C12 * E1;
            const float f14 = f13 * C12 * E3;
            const float f15 = f14 * C12 * E5;
            hi2 = (uint32)pk4(f8, f9, f10, f11)
                | ((ull)(uint32)pk4(A12, f13, f14, f15) << 32);
        }
        *(ull*)(featF8 + e * FS + 16 + mn * 16)     = lo;
        *(ull*)(featF8 + e * FS + 16 + mn * 16 + 8) = hi2;
    }
}

__device__ __forceinline__ f32x16 gemm26(const unsigned char* fb, const long* wreg) {
    f32x16 acc = {0.f, 0.f, 0.f, 0.f, 0.f, 0.f, 0.f, 0.f,
                  0.f, 0.f, 0.f, 0.f, 0.f, 0.f, 0.f, 0.f};
    __builtin_amdgcn_s_setprio(1);
#pragma unroll
    for (int ks = 0; ks < 26; ++ks) {
        const long a = *(const long*)(fb + ks * 16);
        acc = __builtin_amdgcn_mfma_f32_32x32x16_fp8_fp8(wreg[ks], a, acc, 0, 0, 0);
    }
    __builtin_amdgcn_s_setprio(0);
    return acc;
}

__device__ __forceinline__ void partials(
    const f32x16& acc, float (*pSb)[4], float (*pQb)[4],
    int e32, int cg, int hi) {
    float s = 0.f, q = 0.f;
#pragma unroll
    for (int r = 0; r < 16; ++r) { s += acc[r]; q += acc[r] * acc[r]; }
    s += __shfl_xor(s, 32, 64);
    q += __shfl_xor(q, 32, 64);
    if (hi == 0) { pSb[e32][cg] = s; pQb[e32][cg] = q; }
}

__device__ __forceinline__ void ln_store(
    const f32x16& acc, const float (*pSb)[4], const float (*pQb)[4],
    int e32, int cg, int hi, int myrow,
    const float* gbuf, const float* bbuf, float* __restrict__ outE) {
    const float4 ps = *(const float4*)&pSb[e32][0];
    const float4 pq = *(const float4*)&pQb[e32][0];
    const float s = ps.x + ps.y + ps.z + ps.w;
    const float q = pq.x + pq.y + pq.z + pq.w;
    const float mean = s * (1.0f / 128.0f);
    const float rstd = rsqrtf(q * (1.0f / 128.0f) - mean * mean + 1e-5f);
    const int cb = cg * 32 + hi * 4;
    float* orow = outE + ((size_t)myrow * KNB + e32) * HID + cb;
#pragma unroll
    for (int j = 0; j < 4; ++j) {
        const float4 gg = *(const float4*)&gbuf[cb + 8 * j];
        const float4 bb = *(const float4*)&bbuf[cb + 8 * j];
        float4 o;
        o.x = (acc[4 * j + 0] - mean) * rstd * gg.x + bb.x;
        o.y = (acc[4 * j + 1] - mean) * rstd * gg.y + bb.y;
        o.z = (acc[4 * j + 2] - mean) * rstd * gg.z + bb.z;
        o.w = (acc[4 * j + 3] - mean) * rstd * gg.w + bb.w;
        *(float4*)(orow + 8 * j) = o;
    }
}

__global__ __launch_bounds__(256, 4) void edge_kernel(
    const float* __restrict__ X,
    const int* __restrict__ Ridx, const int* __restrict__ Chain,
    const float* __restrict__ W_pos, const float* __restrict__ b_pos,
    const unsigned char* __restrict__ Wf8,
    const float* __restrict__ lng, const float* __restrict__ lnb,
    const float* __restrict__ eidx_f, float* __restrict__ outE) {
    const int tid = threadIdx.x;
    const int row0 = blockIdx.x * 4;
    const int b = row0 >> 11;                 // 2048 % 4 == 0: no batch straddle
    const int i0 = row0 & (LEN - 1);

    __shared__ __align__(16) unsigned char featF8[2][FBSZ];     // 28160 B
    __shared__ __align__(4) __bf16 natoms[4][32][NST];          //  4864 B
    __shared__ __bf16 iatoms[4][16];                            //   128 B
    __shared__ __bf16 wposL[16 * 66];                           //  2112 B
    __shared__ __align__(16) float pS[2][32][4], pQ[2][32][4];  //  2048 B
    __shared__ float gbuf[HID], bbuf[HID];                      //  1024 B
    __shared__ int jR[4][KNB], jC[4][KNB];                      //  1024 B
    __shared__ int riS[4], ciS[4];                              //    32 B
    // total ~39.4 KB -> 4 blocks/CU

    const float* Xb = X + (size_t)b * LEN * 12;

    const int cg = tid >> 6, l = tid & 63;
    const int e32 = l & 31, hi = l >> 5;

    // --- W register residency: W[cg*32+e32][k], 26 steps x 8B = 52 VGPRs.
    long wreg[26];
    {
        const unsigned char* wb = Wf8 + (size_t)(cg * 32 + e32) * 416 + hi * 8;
#pragma unroll
        for (int ks = 0; ks < 26; ++ks)
            wreg[ks] = *(const long*)(wb + ks * 16);
    }

    // --- prologue: wposL (bf16); gamma/beta; all 4 rows' gathers
    for (int t = tid; t < 1056; t += 256)
        wposL[t] = (__bf16)(W_pos[t] + b_pos[t / 66]);
    if (tid < 128) {
        const int r = tid >> 5, e = tid & 31;
        const int j = (int)eidx_f[(size_t)(row0 + r) * KNB + e];
        jR[r][e] = Ridx[b * LEN + j];
        jC[r][e] = Chain[b * LEN + j];
        load_res_atoms_bf(Xb + j * 12, &natoms[r][e][0]);
        gbuf[tid] = lng[tid];
        bbuf[tid] = lnb[tid];
    } else if (tid < 132) {
        const int r = tid - 128;
        load_res_atoms_bf(Xb + (size_t)(i0 + r) * 12, &iatoms[r][0]);
    } else if (tid < 136) {
        riS[tid - 132] = Ridx[b * LEN + i0 + (tid - 132)];
    } else if (tid < 140) {
        ciS[tid - 136] = Chain[b * LEN + i0 + (tid - 136)];
    }
    bar_lgkm();

    compute_features(tid, riS[0], ciS[0], wposL, jR[0], jC[0],
                     natoms[0], iatoms[0], featF8[0]);
    bar_lgkm();

    const unsigned char* fb0 = featF8[0] + e32 * FS + hi * 8;
    const unsigned char* fb1 = featF8[1] + e32 * FS + hi * 8;
    f32x16 acc;

    // region 0: GEMM(row0,buf0) | features(row1->buf1) | partials ping0
    acc = gemm26(fb0, wreg);
    compute_features(tid, riS[1], ciS[1], wposL, jR[1], jC[1],
                     natoms[1], iatoms[1], featF8[1]);
    partials(acc, pS[0], pQ[0], e32, cg, hi);
    bar_lgkm();

    // region 1: LN(row0,ping0) | GEMM(row1,buf1) | features(row2->buf0) | ping1
    ln_store(acc, pS[0], pQ[0], e32, cg, hi, row0 + 0, gbuf, bbuf, outE);
    acc = gemm26(fb1, wreg);
    compute_features(tid, riS[2], ciS[2], wposL, jR[2], jC[2],
                     natoms[2], iatoms[2], featF8[0]);
    partials(acc, pS[1], pQ[1], e32, cg, hi);
    bar_lgkm();

    // region 2: LN(row1,ping1) | GEMM(row2,buf0) | features(row3->buf1) | ping0
    ln_store(acc, pS[1], pQ[1], e32, cg, hi, row0 + 1, gbuf, bbuf, outE);
    acc = gemm26(fb0, wreg);
    compute_features(tid, riS[3], ciS[3], wposL, jR[3], jC[3],
                     natoms[3], iatoms[3], featF8[1]);
    partials(acc, pS[0], pQ[0], e32, cg, hi);
    bar_lgkm();

    // region 3: LN(row2,ping0) | GEMM(row3,buf1) | ping1
    ln_store(acc, pS[0], pQ[0], e32, cg, hi, row0 + 2, gbuf, bbuf, outE);
    acc = gemm26(fb1, wreg);
    partials(acc, pS[1], pQ[1], e32, cg, hi);
    bar_lgkm();

    // epilogue: LN(row3,ping1)
    ln_store(acc, pS[1], pQ[1], e32, cg, hi, row0 + 3, gbuf, bbuf, outE);
}

extern "C" void kernel_launch(void* const* d_in, const int* in_sizes, int n_in,
                              void* d_out, int out_size, void* d_ws, size_t ws_size,
                              hipStream_t stream) {
    const float* X      = (const float*)d_in[0];
    const float* mask   = (const float*)d_in[1];
    const int*   Ridx   = (const int*)d_in[2];
    const int*   Chain  = (const int*)d_in[3];
    const float* W_pos  = (const float*)d_in[4];
    const float* b_pos  = (const float*)d_in[5];
    const float* W_edge = (const float*)d_in[6];
    const float* lng    = (const float*)d_in[7];
    const float* lnb    = (const float*)d_in[8];

    float* out  = (float*)d_out;
    float* eidx = out;                           // B*L*K floats (exact ints)
    float* E    = out + (size_t)2 * LEN * KNB;   // B*L*K*HID floats

    unsigned char* Wf8 = (unsigned char*)d_ws;   // 52 KiB

    const int nrow = 2 * LEN;
    topk_kernel<<<nrow / 4 + 52, 256, 0, stream>>>(X, mask, W_edge, (int*)Wf8, eidx);
    edge_kernel<<<nrow / 4, 256, 0, stream>>>(X, Ridx, Chain, W_pos, b_pos, Wf8,
                                              lng, lnb, eidx, E);
}

// Round 19
// 52.998 us; speedup vs baseline: 1.2441x; 1.2441x over previous
//
#include <hip/hip_runtime.h>
#include <hip/hip_bf16.h>

#define LEN   2048
#define KNB   32
#define HID   128
#define FS    440            // fp8 bytes/feature-row; 110 dw % 32 = 14 -> uniform banks
#define FBSZ  (32 * FS)      // 14080 B per feature buffer
#define NST   19             // natoms bf16 stride: 38B -> ~2-way max (free, m136)

typedef unsigned long long ull;
typedef unsigned int uint32;
typedef float f32x4  __attribute__((ext_vector_type(4)));
typedef float f32x16 __attribute__((ext_vector_type(16)));

// LDS-only barrier: output stores (vmcnt) stay in flight across rows.
__device__ __forceinline__ void bar_lgkm() {
    asm volatile("s_waitcnt lgkmcnt(0)" ::: "memory");
    __builtin_amdgcn_s_barrier();
    asm volatile("" ::: "memory");
}

// ---------------------------------------------------------------------------
// Kernel 1 (R17 proven version): blocks 0..4095 — exact top-K=32 via
// histogram-select, keys in registers, 1 row/block (high block-parallelism;
// R18's LDS-staged 4-row variant regressed 4x — serialization beat L2 savings).
// Blocks 4096+ — W_edge f32 -> fp8 e4m3.
// ---------------------------------------------------------------------------
__global__ __launch_bounds__(256) void topk_kernel(
    const float* __restrict__ X, const float* __restrict__ mask,
    const float* __restrict__ W_edge, int* __restrict__ Wf8,
    float* __restrict__ eidx_out) {
    const int bid = blockIdx.x;
    const int tid = threadIdx.x;

    if (bid >= 2 * LEN) {    // W-convert tail blocks
        const int t = (bid - 2 * LEN) * 256 + tid;
        if (t < 13312) {
            const float4 w = ((const float4*)W_edge)[t];
            int r = __builtin_amdgcn_cvt_pk_fp8_f32(w.x, w.y, 0, false);
            r = __builtin_amdgcn_cvt_pk_fp8_f32(w.z, w.w, r, true);
            Wf8[t] = r;
        }
        return;
    }

    const int row = bid;
    const int b = row >> 11;
    const int i = row & (LEN - 1);

    __shared__ int hist[512];
    __shared__ ull cand[LEN];
    __shared__ int candcnt;
    __shared__ int selB;

    const float* Xb = X + (size_t)b * LEN * 12;
    const float* mb = mask + (size_t)b * LEN;
    const float cax = Xb[i * 12 + 3];
    const float cay = Xb[i * 12 + 4];
    const float caz = Xb[i * 12 + 5];

    uint32 d2b[8];
#pragma unroll
    for (int q = 0; q < 8; ++q) {
        const int j = q * 256 + tid;
        const float4 ld0 = *(const float4*)(Xb + j * 12);      // N.x N.y N.z CA.x
        const float4 ld1 = *(const float4*)(Xb + j * 12 + 4);  // CA.y CA.z C.x C.y
        float dx = __fsub_rn(cax, ld0.w);
        float dy = __fsub_rn(cay, ld1.x);
        float dz = __fsub_rn(caz, ld1.y);
        float d2 = __fadd_rn(__fadd_rn(__fmul_rn(dx, dx), __fmul_rn(dy, dy)),
                             __fmul_rn(dz, dz));
        d2 = __fadd_rn(d2, __fmul_rn(__fsub_rn(1.0f, mb[j]), 1000000.0f));
        d2b[q] = __float_as_uint(d2);
    }

    hist[tid] = 0; hist[tid + 256] = 0;
    if (tid == 0) candcnt = 0;
    __syncthreads();
#pragma unroll
    for (int q = 0; q < 8; ++q) atomicAdd(&hist[d2b[q] >> 22], 1);
    __syncthreads();

    if (tid < 64) {
        int loc[8];
        int s = 0;
#pragma unroll
        for (int t = 0; t < 8; ++t) { loc[t] = hist[tid * 8 + t]; s += loc[t]; }
        int incl = s;
#pragma unroll
        for (int off = 1; off < 64; off <<= 1) {
            int o = __shfl_up(incl, off, 64);
            if (tid >= off) incl += o;
        }
        const int excl = incl - s;
        if (excl < KNB && incl >= KNB) {
            int c = excl;
#pragma unroll
            for (int t = 0; t < 8; ++t) {
                int c2 = c + loc[t];
                if (c < KNB && c2 >= KNB) selB = tid * 8 + t;
                c = c2;
            }
        }
    }
    __syncthreads();
    const uint32 B = (uint32)selB;

#pragma unroll
    for (int q = 0; q < 8; ++q) {
        if ((d2b[q] >> 22) <= B) {
            int p = atomicAdd(&candcnt, 1);
            cand[p] = (((ull)d2b[q]) << 32) | (uint32)(q * 256 + tid);
        }
    }
    __syncthreads();
    const int M = candcnt;

    for (int c = tid; c < M; c += 256) {
        const ull k = cand[c];
        int r = 0;
        for (int m = 0; m < M; ++m) r += (cand[m] < k);
        if (r < KNB)
            eidx_out[(size_t)row * KNB + r] = (float)(uint32)(k & 0xFFFFFFFFull);
    }
}

// ---------------------------------------------------------------------------
// Kernel 2: 256 thr (4 waves), 4 rows/block, 1024 blocks -> 4 blocks/CU.
// Per row, ONE barrier: [LN(prev acc) | GEMM(cur, setprio-boosted) |
// features(next) | partials ping-pong] bar. W reg-resident fp8 (52 VGPR);
// atoms bf16 @ stride 19 (conflict-free).
// ---------------------------------------------------------------------------
__device__ __forceinline__ void load_res_atoms_bf(const float* __restrict__ p, __bf16* dst) {
    const float Nx = p[0], Ny = p[1], Nz = p[2];
    const float Ax = p[3], Ay = p[4], Az = p[5];
    const float Cx = p[6], Cy = p[7], Cz = p[8];
    const float Ox = p[9], Oy = p[10], Oz = p[11];
    const float bx = Ax - Nx, by = Ay - Ny, bz = Az - Nz;
    const float cx = Cx - Ax, cy = Cy - Ay, cz = Cz - Az;
    const float axv = by * cz - bz * cy;
    const float ayv = bz * cx - bx * cz;
    const float azv = bx * cy - by * cx;
    dst[0] = (__bf16)Nx;  dst[1] = (__bf16)Ny;  dst[2] = (__bf16)Nz;
    dst[3] = (__bf16)Ax;  dst[4] = (__bf16)Ay;  dst[5] = (__bf16)Az;
    dst[6] = (__bf16)Cx;  dst[7] = (__bf16)Cy;  dst[8] = (__bf16)Cz;
    dst[9] = (__bf16)Ox;  dst[10] = (__bf16)Oy; dst[11] = (__bf16)Oz;
    dst[12] = (__bf16)(-0.58273431f * axv + 0.56802827f * bx + -0.54067466f * cx + Ax);
    dst[13] = (__bf16)(-0.58273431f * ayv + 0.56802827f * by + -0.54067466f * cy + Ay);
    dst[14] = (__bf16)(-0.58273431f * azv + 0.56802827f * bz + -0.54067466f * cz + Az);
}

__device__ __forceinline__ int pk4(float a, float b, float c, float d) {
    int r = __builtin_amdgcn_cvt_pk_fp8_f32(a, b, 0, false);
    return __builtin_amdgcn_cvt_pk_fp8_f32(c, d, r, true);
}

// chain constants exp(-1.1377778 * (2j+1)), j = 0..3
#define E1  3.2053337e-1f
#define E3  3.2931300e-2f
#define E5  3.3834001e-3f
#define E7  3.4760500e-4f

__device__ __forceinline__ void compute_features(
    int tid, int Ri, int Ci,
    const __bf16* __restrict__ wposL,
    const int* jR, const int* jC,
    const __bf16 (*natoms)[NST], const __bf16* iatoms,
    unsigned char* featF8) {
#pragma unroll
    for (int it = 0; it < 2; ++it) {           // pos-enc: 512 tasks
        const int task = tid + it * 256;
        const int e = task >> 4, p = task & 15;
        const int drel = jR[e] - Ri;
        const int same = (jC[e] == Ci);
        int dc = drel + 32;
        dc = dc < 0 ? 0 : (dc > 64 ? 64 : dc);
        const int df = same ? dc : 65;
        const float v = (float)wposL[p * 66 + df];
        const int pb = __builtin_amdgcn_cvt_pk_fp8_f32(v, 0.0f, 0, false);
        featF8[e * FS + p] = (unsigned char)(pb & 0xFF);
    }
    for (int task = tid; task < 800; task += 256) {   // rbf: 800 tasks
        const int mn = task >> 5, e = task & 31;
        const int m = mn / 5, n = mn - m * 5;
        const float ax = (float)iatoms[m * 3 + 0];
        const float ay = (float)iatoms[m * 3 + 1];
        const float az = (float)iatoms[m * 3 + 2];
        const float dx = ax - (float)natoms[e][n * 3 + 0];
        const float dy = ay - (float)natoms[e][n * 3 + 1];
        const float dz = az - (float)natoms[e][n * 3 + 2];
        const float D = sqrtf(dx * dx + dy * dy + dz * dz + 1e-6f);
        const float Dc = fminf(D, 40.0f);
        const float v4 = Dc - 7.3333333f;
        const float A4  = __expf(-0.64f * v4 * v4);
        const float C4  = __expf(1.7066667f * v4);
        const float Ci4 = 1.0f / C4;
        ull lo, hi2;
        {
            const float f3 = A4 * Ci4 * E1;
            const float f2 = f3 * Ci4 * E3;
            const float f1 = f2 * Ci4 * E5;
            const float f0 = f1 * Ci4 * E7;
            const float f5 = A4 * C4 * E1;
            const float f6 = f5 * C4 * E3;
            const float f7 = f6 * C4 * E5;
            lo = (uint32)pk4(f0, f1, f2, f3)
               | ((ull)(uint32)pk4(A4, f5, f6, f7) << 32);
        }
        const float v12 = Dc - 18.0f;
        const float A12  = __expf(-0.64f * v12 * v12);
        const float C12  = C4 * 1.24140e-8f;
        const float Ci12 = Ci4 * 8.05543e7f;
        {
            const float f11 = A12 * Ci12 * E1;
            const float f10 = f11 * Ci12 * E3;
            const float f9  = f10 * Ci12 * E5;
            const float f8  = f9  * Ci12 * E7;
            const float f13 = A12 * C12 * E1;
            const float f14 = f13 * C12 * E3;
            const float f15 = f14 * C12 * E5;
            hi2 = (uint32)pk4(f8, f9, f10, f11)
                | ((ull)(uint32)pk4(A12, f13, f14, f15) << 32);
        }
        *(ull*)(featF8 + e * FS + 16 + mn * 16)     = lo;
        *(ull*)(featF8 + e * FS + 16 + mn * 16 + 8) = hi2;
    }
}

__device__ __forceinline__ f32x16 gemm26(const unsigned char* fb, const long* wreg) {
    f32x16 acc = {0.f, 0.f, 0.f, 0.f, 0.f, 0.f, 0.f, 0.f,
                  0.f, 0.f, 0.f, 0.f, 0.f, 0.f, 0.f, 0.f};
    __builtin_amdgcn_s_setprio(1);
#pragma unroll
    for (int ks = 0; ks < 26; ++ks) {
        const long a = *(const long*)(fb + ks * 16);
        acc = __builtin_amdgcn_mfma_f32_32x32x16_fp8_fp8(wreg[ks], a, acc, 0, 0, 0);
    }
    __builtin_amdgcn_s_setprio(0);
    return acc;
}

__device__ __forceinline__ void partials(
    const f32x16& acc, float (*pSb)[4], float (*pQb)[4],
    int e32, int cg, int hi) {
    float s = 0.f, q = 0.f;
#pragma unroll
    for (int r = 0; r < 16; ++r) { s += acc[r]; q += acc[r] * acc[r]; }
    s += __shfl_xor(s, 32, 64);
    q += __shfl_xor(q, 32, 64);
    if (hi == 0) { pSb[e32][cg] = s; pQb[e32][cg] = q; }
}

__device__ __forceinline__ void ln_store(
    const f32x16& acc, const float (*pSb)[4], const float (*pQb)[4],
    int e32, int cg, int hi, int myrow,
    const float* gbuf, const float* bbuf, float* __restrict__ outE) {
    const float4 ps = *(const float4*)&pSb[e32][0];
    const float4 pq = *(const float4*)&pQb[e32][0];
    const float s = ps.x + ps.y + ps.z + ps.w;
    const float q = pq.x + pq.y + pq.z + pq.w;
    const float mean = s * (1.0f / 128.0f);
    const float rstd = rsqrtf(q * (1.0f / 128.0f) - mean * mean + 1e-5f);
    const int cb = cg * 32 + hi * 4;
    float* orow = outE + ((size_t)myrow * KNB + e32) * HID + cb;
#pragma unroll
    for (int j = 0; j < 4; ++j) {
        const float4 gg = *(const float4*)&gbuf[cb + 8 * j];
        const float4 bb = *(const float4*)&bbuf[cb + 8 * j];
        float4 o;
        o.x = (acc[4 * j + 0] - mean) * rstd * gg.x + bb.x;
        o.y = (acc[4 * j + 1] - mean) * rstd * gg.y + bb.y;
        o.z = (acc[4 * j + 2] - mean) * rstd * gg.z + bb.z;
        o.w = (acc[4 * j + 3] - mean) * rstd * gg.w + bb.w;
        *(float4*)(orow + 8 * j) = o;
    }
}

__global__ __launch_bounds__(256, 4) void edge_kernel(
    const float* __restrict__ X,
    const int* __restrict__ Ridx, const int* __restrict__ Chain,
    const float* __restrict__ W_pos, const float* __restrict__ b_pos,
    const unsigned char* __restrict__ Wf8,
    const float* __restrict__ lng, const float* __restrict__ lnb,
    const float* __restrict__ eidx_f, float* __restrict__ outE) {
    const int tid = threadIdx.x;
    const int row0 = blockIdx.x * 4;
    const int b = row0 >> 11;                 // 2048 % 4 == 0: no batch straddle
    const int i0 = row0 & (LEN - 1);

    __shared__ __align__(16) unsigned char featF8[2][FBSZ];     // 28160 B
    __shared__ __align__(4) __bf16 natoms[4][32][NST];          //  4864 B
    __shared__ __bf16 iatoms[4][16];                            //   128 B
    __shared__ __bf16 wposL[16 * 66];                           //  2112 B
    __shared__ __align__(16) float pS[2][32][4], pQ[2][32][4];  //  2048 B
    __shared__ float gbuf[HID], bbuf[HID];                      //  1024 B
    __shared__ int jR[4][KNB], jC[4][KNB];                      //  1024 B
    __shared__ int riS[4], ciS[4];                              //    32 B
    // total ~39.4 KB -> 4 blocks/CU

    const float* Xb = X + (size_t)b * LEN * 12;

    const int cg = tid >> 6, l = tid & 63;
    const int e32 = l & 31, hi = l >> 5;

    // --- W register residency: W[cg*32+e32][k], 26 steps x 8B = 52 VGPRs.
    long wreg[26];
    {
        const unsigned char* wb = Wf8 + (size_t)(cg * 32 + e32) * 416 + hi * 8;
#pragma unroll
        for (int ks = 0; ks < 26; ++ks)
            wreg[ks] = *(const long*)(wb + ks * 16);
    }

    // --- prologue: wposL (bf16); gamma/beta; all 4 rows' gathers
    for (int t = tid; t < 1056; t += 256)
        wposL[t] = (__bf16)(W_pos[t] + b_pos[t / 66]);
    if (tid < 128) {
        const int r = tid >> 5, e = tid & 31;
        const int j = (int)eidx_f[(size_t)(row0 + r) * KNB + e];
        jR[r][e] = Ridx[b * LEN + j];
        jC[r][e] = Chain[b * LEN + j];
        load_res_atoms_bf(Xb + j * 12, &natoms[r][e][0]);
        gbuf[tid] = lng[tid];
        bbuf[tid] = lnb[tid];
    } else if (tid < 132) {
        const int r = tid - 128;
        load_res_atoms_bf(Xb + (size_t)(i0 + r) * 12, &iatoms[r][0]);
    } else if (tid < 136) {
        riS[tid - 132] = Ridx[b * LEN + i0 + (tid - 132)];
    } else if (tid < 140) {
        ciS[tid - 136] = Chain[b * LEN + i0 + (tid - 136)];
    }
    bar_lgkm();

    compute_features(tid, riS[0], ciS[0], wposL, jR[0], jC[0],
                     natoms[0], iatoms[0], featF8[0]);
    bar_lgkm();

    const unsigned char* fb0 = featF8[0] + e32 * FS + hi * 8;
    const unsigned char* fb1 = featF8[1] + e32 * FS + hi * 8;
    f32x16 acc;

    // region 0: GEMM(row0,buf0) | features(row1->buf1) | partials ping0
    acc = gemm26(fb0, wreg);
    compute_features(tid, riS[1], ciS[1], wposL, jR[1], jC[1],
                     natoms[1], iatoms[1], featF8[1]);
    partials(acc, pS[0], pQ[0], e32, cg, hi);
    bar_lgkm();

    // region 1: LN(row0,ping0) | GEMM(row1,buf1) | features(row2->buf0) | ping1
    ln_store(acc, pS[0], pQ[0], e32, cg, hi, row0 + 0, gbuf, bbuf, outE);
    acc = gemm26(fb1, wreg);
    compute_features(tid, riS[2], ciS[2], wposL, jR[2], jC[2],
                     natoms[2], iatoms[2], featF8[0]);
    partials(acc, pS[1], pQ[1], e32, cg, hi);
    bar_lgkm();

    // region 2: LN(row1,ping1) | GEMM(row2,buf0) | features(row3->buf1) | ping0
    ln_store(acc, pS[1], pQ[1], e32, cg, hi, row0 + 1, gbuf, bbuf, outE);
    acc = gemm26(fb0, wreg);
    compute_features(tid, riS[3], ciS[3], wposL, jR[3], jC[3],
                     natoms[3], iatoms[3], featF8[1]);
    partials(acc, pS[0], pQ[0], e32, cg, hi);
    bar_lgkm();

    // region 3: LN(row2,ping0) | GEMM(row3,buf1) | ping1
    ln_store(acc, pS[0], pQ[0], e32, cg, hi, row0 + 2, gbuf, bbuf, outE);
    acc = gemm26(fb1, wreg);
    partials(acc, pS[1], pQ[1], e32, cg, hi);
    bar_lgkm();

    // epilogue: LN(row3,ping1)
    ln_store(acc, pS[1], pQ[1], e32, cg, hi, row0 + 3, gbuf, bbuf, outE);
}

extern "C" void kernel_launch(void* const* d_in, const int* in_sizes, int n_in,
                              void* d_out, int out_size, void* d_ws, size_t ws_size,
                              hipStream_t stream) {
    const float* X      = (const float*)d_in[0];
    const float* mask   = (const float*)d_in[1];
    const int*   Ridx   = (const int*)d_in[2];
    const int*   Chain  = (const int*)d_in[3];
    const float* W_pos  = (const float*)d_in[4];
    const float* b_pos  = (const float*)d_in[5];
    const float* W_edge = (const float*)d_in[6];
    const float* lng    = (const float*)d_in[7];
    const float* lnb    = (const float*)d_in[8];

    float* out  = (float*)d_out;
    float* eidx = out;                           // B*L*K floats (exact ints)
    float* E    = out + (size_t)2 * LEN * KNB;   // B*L*K*HID floats

    unsigned char* Wf8 = (unsigned char*)d_ws;   // 52 KiB

    const int nrow = 2 * LEN;
    topk_kernel<<<nrow + 52, 256, 0, stream>>>(X, mask, W_edge, (int*)Wf8, eidx);
    edge_kernel<<<nrow / 4, 256, 0, stream>>>(X, Ridx, Chain, W_pos, b_pos, Wf8,
                                              lng, lnb, eidx, E);
}